// Round 7
// baseline (320.216 us; speedup 1.0000x reference)
//
#include <hip/hip_runtime.h>
#include <cstdint>

typedef __attribute__((ext_vector_type(8))) short short8;
typedef __attribute__((ext_vector_type(4))) float floatx4;
typedef __attribute__((ext_vector_type(8))) int intx8;

__device__ __forceinline__ unsigned short f2bf(float f) {
  unsigned int u = __float_as_uint(f);
  u += 0x7fffu + ((u >> 16) & 1u);   // RNE, finite inputs
  return (unsigned short)(u >> 16);
}

// ---------- GroupNorm partial sums + out:=x (residual init) ----------------
__global__ __launch_bounds__(256) void gn_partial_kernel(
    const float* __restrict__ x, float* __restrict__ gsums,
    float* __restrict__ out) {
  const int b = blockIdx.x >> 8;
  const int g = (blockIdx.x >> 3) & 31;
  const int e = blockIdx.x & 7;
  const long long off = ((long long)(b * 512 + g * 16)) * 4096;
  const float4* xp = (const float4*)(x + off) + e * 2048;
  float4* op = (float4*)(out + off) + e * 2048;
  float s = 0.f, ss = 0.f;
  for (int i = threadIdx.x; i < 2048; i += 256) {
    float4 v = xp[i];
    op[i] = v;
    s  += v.x + v.y + v.z + v.w;
    ss += v.x * v.x + v.y * v.y + v.z * v.z + v.w * v.w;
  }
  for (int off2 = 32; off2; off2 >>= 1) { s += __shfl_down(s, off2); ss += __shfl_down(ss, off2); }
  __shared__ float sb[8];
  const int lane = threadIdx.x & 63, wave = threadIdx.x >> 6;
  if (lane == 0) { sb[wave] = s; sb[4 + wave] = ss; }
  __syncthreads();
  if (threadIdx.x == 0) {
    atomicAdd(gsums + (b * 32 + g) * 2,     sb[0] + sb[1] + sb[2] + sb[3]);
    atomicAdd(gsums + (b * 32 + g) * 2 + 1, sb[4] + sb[5] + sb[6] + sb[7]);
  }
}

// ---------------- GroupNorm finalize: scale/shift per (b,c) ----------------
__global__ __launch_bounds__(256) void gn_finalize_kernel(
    const float* __restrict__ gsums, const float* __restrict__ gamma,
    const float* __restrict__ beta, float* __restrict__ scale,
    float* __restrict__ shift) {
  const int i = blockIdx.x * 256 + threadIdx.x;  // 0..2047
  const int b = i >> 9;
  const int c = i & 511;
  const int g = c >> 4;
  const float S  = gsums[(b * 32 + g) * 2];
  const float SS = gsums[(b * 32 + g) * 2 + 1];
  const float mean = S * (1.f / 65536.f);
  const float var  = SS * (1.f / 65536.f) - mean * mean;
  const float inv  = rsqrtf(var + 1e-5f);
  const float sc = gamma[c] * inv;
  scale[i] = sc;
  shift[i] = beta[c] - mean * sc;
}

// -------- weights fp32 -> bf16, fused with scratch zeroing -----------------
__global__ __launch_bounds__(256) void wcvt_zero_kernel(
    const float* __restrict__ wq, const float* __restrict__ wk,
    const float* __restrict__ wv, unsigned short* __restrict__ w16,
    float* __restrict__ zp, int nzero) {
  const int gi = blockIdx.x * 256 + threadIdx.x;
  if (gi < 196608) {
    const int m = gi >> 16;            // 0..2
    const int i = gi & 65535;          // *4 elems
    const float* src = (m == 0) ? wq : (m == 1) ? wk : wv;
    float4 v = *((const float4*)src + i);
    ushort4 o;
    o.x = f2bf(v.x); o.y = f2bf(v.y); o.z = f2bf(v.z); o.w = f2bf(v.w);
    *((ushort4*)(w16 + (long long)m * 262144) + i) = o;
  } else {
    const int zi = gi - 196608;
    if (zi < nzero) zp[zi] = 0.f;
  }
}

// -------- normalize + transpose: x (B,C,N) fp32 -> xnt (B,N,C) bf16 --------
__global__ __launch_bounds__(256) void norm_transpose_kernel(
    const float* __restrict__ x, const float* __restrict__ scale,
    const float* __restrict__ shift, unsigned short* __restrict__ xnt) {
  const int b = blockIdx.z;
  const int n0 = blockIdx.x * 64;
  const int c0 = blockIdx.y * 64;
  const int t = threadIdx.x;
  __shared__ unsigned short tile[64][65];
  {
    const int cl = t >> 2;
    const int nc = (t & 3) * 16;
    const int c = c0 + cl;
    const float* xp = x + ((long long)b * 512 + c) * 4096 + n0 + nc;
    const float sc = scale[b * 512 + c];
    const float sh = shift[b * 512 + c];
#pragma unroll
    for (int j = 0; j < 16; j += 4) {
      float4 v = *(const float4*)(xp + j);
      tile[cl][nc + j + 0] = f2bf(v.x * sc + sh);
      tile[cl][nc + j + 1] = f2bf(v.y * sc + sh);
      tile[cl][nc + j + 2] = f2bf(v.z * sc + sh);
      tile[cl][nc + j + 3] = f2bf(v.w * sc + sh);
    }
  }
  __syncthreads();
  {
    const int nl = t >> 2;
    const int cc = (t & 3) * 16;
    union { unsigned short u[16]; uint4 q[2]; } o;
#pragma unroll
    for (int j = 0; j < 16; ++j) o.u[j] = tile[cc + j][nl];
    unsigned short* op = xnt + ((long long)b * 4096 + n0 + nl) * 512 + c0 + cc;
    *((uint4*)op) = o.q[0];
    *((uint4*)op + 1) = o.q[1];
  }
}

// ---------------- zero scratch (per-batch path re-zero) --------------------
__global__ __launch_bounds__(256) void zero_kernel(float* __restrict__ p, int n) {
  const int i = blockIdx.x * 256 + threadIdx.x;
  if (i < n) p[i] = 0.f;
}

// ---------------- TN GEMM (bf16), m97 structure + LDS xor-swizzle ----------
// C[m,n] = sum_k A[m*lda+k] * B[n*ldb+k]
// EPI: 2 = bf16 out + bias[m] (LDS-bounce coalesced store)
//      6 = QK-proj: fp8 e4m3 out TRANSPOSED (rows=col-dim tokens), bias[m]
//          split bias/bias2 at m=512; C treated as u8, ldc/sC in bytes.
template <int EPI>
__global__ __launch_bounds__(256) void gemm_tn_kernel(
    const unsigned short* __restrict__ A, const unsigned short* __restrict__ B,
    void* __restrict__ C, const float* __restrict__ bias,
    const float* __restrict__ bias2,
    int lda, int ldb, int ldc, int K,
    long long sA, long long sB, long long sC) {
  const int tid = threadIdx.x;
  const int lane = tid & 63;
  const int wave = tid >> 6;
  const int m0 = blockIdx.x * 128;
  const int n0 = blockIdx.y * 128;
  const int bz = blockIdx.z;
  A += (long long)bz * sA;
  B += (long long)bz * sB;

  __shared__ unsigned short smem[17408];  // 34816 B
  unsigned short* As = smem;
  unsigned short* Bs = smem + 8192;

  floatx4 acc[4][4];
#pragma unroll
  for (int i = 0; i < 4; ++i)
#pragma unroll
    for (int j = 0; j < 4; ++j) acc[i][j] = (floatx4){0.f, 0.f, 0.f, 0.f};

  const unsigned short* ag[4];
  const unsigned short* bg[4];
  unsigned ldsoff[4];
#pragma unroll
  for (int i = 0; i < 4; ++i) {
    const int idx = i * 256 + tid;   // 16B granule within 128x64 tile
    const int r = idx >> 3;
    const int g = idx & 7;
    const int gs = g ^ (r & 7);      // xor-swizzled global granule
    ag[i] = A + (long long)(m0 + r) * lda + gs * 8;
    bg[i] = B + (long long)(n0 + r) * ldb + gs * 8;
    ldsoff[i] = (unsigned)(i * 256 + wave * 64) * 8;
  }

  const int l15 = lane & 15;
  const int wm = (wave >> 1) * 64;
  const int wn = (wave & 1) * 64;

  for (int k0 = 0; k0 < K; k0 += 64) {
#pragma unroll
    for (int i = 0; i < 4; ++i) {
      __builtin_amdgcn_global_load_lds(
          (const __attribute__((address_space(1))) void*)(ag[i] + k0),
          (__attribute__((address_space(3))) void*)(As + ldsoff[i]), 16, 0, 0);
      __builtin_amdgcn_global_load_lds(
          (const __attribute__((address_space(1))) void*)(bg[i] + k0),
          (__attribute__((address_space(3))) void*)(Bs + ldsoff[i]), 16, 0, 0);
    }
    __syncthreads();
#pragma unroll
    for (int kk = 0; kk < 64; kk += 32) {
      const int gq = (kk >> 3) + (lane >> 4);
      short8 af[4], bfr[4];
#pragma unroll
      for (int mt = 0; mt < 4; ++mt) {
        const int row = wm + mt * 16 + l15;
        af[mt] = *(const short8*)&As[row * 64 + ((gq ^ (row & 7)) << 3)];
      }
#pragma unroll
      for (int nt = 0; nt < 4; ++nt) {
        const int row = wn + nt * 16 + l15;
        bfr[nt] = *(const short8*)&Bs[row * 64 + ((gq ^ (row & 7)) << 3)];
      }
#pragma unroll
      for (int mt = 0; mt < 4; ++mt)
#pragma unroll
        for (int nt = 0; nt < 4; ++nt)
          acc[mt][nt] = __builtin_amdgcn_mfma_f32_16x16x32_bf16(
              af[mt], bfr[nt], acc[mt][nt], 0, 0, 0);
    }
    __syncthreads();
  }
  // After final barrier, smem is reusable.

  const int r0 = (lane >> 4) * 4;

  if (EPI == 6) {
    // D row (r-quad) = output channel o (A=weights), col (l15) = token.
    unsigned char* t8 = (unsigned char*)smem;
    const float* bp = (m0 >= 512) ? bias2 : bias;
    const int mb = m0 & 511;
#pragma unroll
    for (int mt = 0; mt < 4; ++mt) {
      const int ml = wm + mt * 16 + r0;   // o-local, multiple of 4
      const float b0 = bp[mb + ml], b1 = bp[mb + ml + 1];
      const float b2 = bp[mb + ml + 2], b3 = bp[mb + ml + 3];
      const int gw = ml >> 4;
      const int mby = ml & 15;
#pragma unroll
      for (int nt = 0; nt < 4; ++nt) {
        const int nl = wn + nt * 16 + l15;  // token-local
        int p = __builtin_amdgcn_cvt_pk_fp8_f32(acc[mt][nt][0] + b0,
                                                acc[mt][nt][1] + b1, 0, false);
        p = __builtin_amdgcn_cvt_pk_fp8_f32(acc[mt][nt][2] + b2,
                                            acc[mt][nt][3] + b3, p, true);
        *(int*)&t8[nl * 128 + ((gw ^ (nl & 7)) << 4) + mby] = p;
      }
    }
    __syncthreads();
    unsigned char* o8 = (unsigned char*)C + (long long)bz * sC;
#pragma unroll
    for (int t = 0; t < 4; ++t) {
      const int gid = t * 256 + tid;
      const int row = gid >> 3;    // token 0..127
      const int gc = gid & 7;
      uint4 v = *(const uint4*)&t8[row * 128 + ((gc ^ (row & 7)) << 4)];
      *(uint4*)&o8[(long long)(n0 + row) * ldc + m0 + gc * 16] = v;
    }
    return;
  }

  // EPI 2: bf16 out + bias[m], LDS bounce
#pragma unroll
  for (int mt = 0; mt < 4; ++mt) {
#pragma unroll
    for (int nt = 0; nt < 4; ++nt) {
      const int nl = wn + nt * 16 + l15;
#pragma unroll
      for (int r = 0; r < 4; ++r) {
        const int ml = wm + mt * 16 + r0 + r;
        smem[ml * 136 + nl] = f2bf(acc[mt][nt][r] + bias[m0 + ml]);
      }
    }
  }
  __syncthreads();
  {
    unsigned short* o = (unsigned short*)C + (long long)bz * sC;
#pragma unroll
    for (int j = 0; j < 8; ++j) {
      const int gid = j * 256 + tid;
      const int m = gid >> 4;
      const int gc = gid & 15;
      short8 v = *(const short8*)&smem[m * 136 + gc * 8];
      *(short8*)&o[(long long)(m0 + m) * ldc + n0 + gc * 8] = v;
    }
  }
}

// -------- S = exp(QK^T * scl) via MX-fp8 MFMA (unit scales) ----------------
__global__ __launch_bounds__(256) void sgemm_fp8_kernel(
    const unsigned char* __restrict__ A, const unsigned char* __restrict__ B,
    unsigned short* __restrict__ S, float* __restrict__ lsum,
    long long sA, long long sB, long long sC, long long sL) {
  const int tid = threadIdx.x;
  const int lane = tid & 63;
  const int wave = tid >> 6;
  const int quad = lane >> 4;
  const int l15 = lane & 15;
  const int j0 = blockIdx.x * 128;
  const int i0 = blockIdx.y * 128;
  const int bz = blockIdx.z;
  A += (long long)bz * sA;
  B += (long long)bz * sB;

  __shared__ unsigned short smem[17408];        // 34816 B
  unsigned char* As = (unsigned char*)smem;     // 128 x 128 B
  unsigned char* Bs = (unsigned char*)smem + 16384;

  floatx4 acc[4][4];
#pragma unroll
  for (int i = 0; i < 4; ++i)
#pragma unroll
    for (int j = 0; j < 4; ++j) acc[i][j] = (floatx4){0.f, 0.f, 0.f, 0.f};

  const unsigned char* ag[4];
  const unsigned char* bg[4];
  unsigned ldsoff[4];
#pragma unroll
  for (int i = 0; i < 4; ++i) {
    const int idx = i * 256 + tid;   // 16B granule within 128x128B tile
    const int r = idx >> 3;
    const int g = idx & 7;
    const int gs = g ^ (r & 7);
    ag[i] = A + (long long)(j0 + r) * 1024 + gs * 16;
    bg[i] = B + (long long)(i0 + r) * 1024 + gs * 16;
    ldsoff[i] = (unsigned)(i * 256 + wave * 64) * 16;
  }

  const int wj = (wave >> 1) * 64;
  const int wi = (wave & 1) * 64;

  for (int k0 = 0; k0 < 512; k0 += 128) {
#pragma unroll
    for (int i = 0; i < 4; ++i) {
      __builtin_amdgcn_global_load_lds(
          (const __attribute__((address_space(1))) void*)(ag[i] + k0),
          (__attribute__((address_space(3))) void*)(As + ldsoff[i]), 16, 0, 0);
      __builtin_amdgcn_global_load_lds(
          (const __attribute__((address_space(1))) void*)(bg[i] + k0),
          (__attribute__((address_space(3))) void*)(Bs + ldsoff[i]), 16, 0, 0);
    }
    __syncthreads();
    intx8 af[4], bq[4];
#pragma unroll
    for (int t = 0; t < 4; ++t) {
      {
        const int row = wj + t * 16 + l15;
        const int r7 = row & 7;
        const uint4 x0 = *(const uint4*)(As + row * 128 + (((2 * quad) ^ r7) << 4));
        const uint4 x1 = *(const uint4*)(As + row * 128 + (((2 * quad + 1) ^ r7) << 4));
        af[t] = (intx8){(int)x0.x, (int)x0.y, (int)x0.z, (int)x0.w,
                        (int)x1.x, (int)x1.y, (int)x1.z, (int)x1.w};
      }
      {
        const int row = wi + t * 16 + l15;
        const int r7 = row & 7;
        const uint4 x0 = *(const uint4*)(Bs + row * 128 + (((2 * quad) ^ r7) << 4));
        const uint4 x1 = *(const uint4*)(Bs + row * 128 + (((2 * quad + 1) ^ r7) << 4));
        bq[t] = (intx8){(int)x0.x, (int)x0.y, (int)x0.z, (int)x0.w,
                        (int)x1.x, (int)x1.y, (int)x1.z, (int)x1.w};
      }
    }
#pragma unroll
    for (int jt = 0; jt < 4; ++jt)
#pragma unroll
      for (int it = 0; it < 4; ++it)
        acc[jt][it] = __builtin_amdgcn_mfma_scale_f32_16x16x128_f8f6f4(
            af[jt], bq[it], acc[jt][it], 0, 0, 0, 127, 0, 127);
    __syncthreads();
  }

  // Epilogue: e = exp(score*SCL); tile [i][j] bf16 (pad 136); b64 writes.
  const float SCL = 0.044194173824159216f;  // 1/sqrt(512)
  const int jr = quad * 4;
  float rs_it[4] = {0.f, 0.f, 0.f, 0.f};
#pragma unroll
  for (int jt = 0; jt < 4; ++jt) {
#pragma unroll
    for (int it = 0; it < 4; ++it) {
      const int il = wi + it * 16 + l15;
      const int jl = wj + jt * 16 + jr;
      unsigned long long pk = 0;
#pragma unroll
      for (int r = 0; r < 4; ++r) {
        const float e = __expf(acc[jt][it][r] * SCL);
        rs_it[it] += e;
        pk |= (unsigned long long)(__float_as_uint(e) >> 16) << (16 * r);
      }
      *(unsigned long long*)&smem[il * 136 + jl] = pk;
    }
  }
  float* lrow = lsum + (long long)bz * sL;
#pragma unroll
  for (int it = 0; it < 4; ++it) {
    float rs = rs_it[it];
    rs += __shfl_xor(rs, 16);
    rs += __shfl_xor(rs, 32);
    if (quad == 0) atomicAdd(lrow + i0 + wi + it * 16 + l15, rs);
  }
  __syncthreads();
  unsigned short* o = S + (long long)bz * sC;
#pragma unroll
  for (int t = 0; t < 8; ++t) {
    const int gid = t * 256 + tid;
    const int row = gid >> 4;
    const int gc = gid & 15;
    short8 v = *(const short8*)&smem[row * 136 + gc * 8];
    *(short8*)&o[(long long)(i0 + row) * 4096 + j0 + gc * 8] = v;
  }
}

// -------- PV: out[c,n] += sum_j V[c,j] P[n,j] / lsum[n]  (split-K x2) ------
// 1D grid; id decoded so the 4 m-tiles of one (n-strip, k-half) land on the
// SAME XCD (id%8) in consecutive slots -> shared S-strip stays in that L2.
// out pre-initialized to residual x; epilogue is fp32 atomicAdd.
__global__ __launch_bounds__(256) void pv_kernel(
    const unsigned short* __restrict__ A,   // V rows (c), stride 4096
    const unsigned short* __restrict__ B,   // S rows (n), stride 4096
    float* __restrict__ out, const float* __restrict__ lsum,
    long long sA, long long sB, long long sC, long long sL) {
  const int id = blockIdx.x;
  const int xcd = id & 7;
  const int slot = id >> 3;
  const int m0 = (slot & 3) * 128;
  const int grp = xcd + 8 * (slot >> 2);
  const int n0 = (grp & 31) * 128;
  const int zz = grp >> 5;            // batch*2 + half (or half if 1 batch)
  const int bz = zz >> 1;
  const int half = zz & 1;
  A += (long long)bz * sA + half * 2048;
  B += (long long)bz * sB + half * 2048;

  const int tid = threadIdx.x;
  const int lane = tid & 63;
  const int wave = tid >> 6;

  __shared__ unsigned short As[8192];
  __shared__ unsigned short Bs[8192];

  floatx4 acc[4][4];
#pragma unroll
  for (int i = 0; i < 4; ++i)
#pragma unroll
    for (int j = 0; j < 4; ++j) acc[i][j] = (floatx4){0.f, 0.f, 0.f, 0.f};

  const unsigned short* ag[4];
  const unsigned short* bg[4];
  unsigned ldsoff[4];
#pragma unroll
  for (int i = 0; i < 4; ++i) {
    const int idx = i * 256 + tid;
    const int r = idx >> 3;
    const int g = idx & 7;
    const int gs = g ^ (r & 7);
    ag[i] = A + (long long)(m0 + r) * 4096 + gs * 8;
    bg[i] = B + (long long)(n0 + r) * 4096 + gs * 8;
    ldsoff[i] = (unsigned)(i * 256 + wave * 64) * 8;
  }

  const int l15 = lane & 15;
  const int wm = (wave >> 1) * 64;
  const int wn = (wave & 1) * 64;

  for (int k0 = 0; k0 < 2048; k0 += 64) {
#pragma unroll
    for (int i = 0; i < 4; ++i) {
      __builtin_amdgcn_global_load_lds(
          (const __attribute__((address_space(1))) void*)(ag[i] + k0),
          (__attribute__((address_space(3))) void*)(As + ldsoff[i]), 16, 0, 0);
      __builtin_amdgcn_global_load_lds(
          (const __attribute__((address_space(1))) void*)(bg[i] + k0),
          (__attribute__((address_space(3))) void*)(Bs + ldsoff[i]), 16, 0, 0);
    }
    __syncthreads();
#pragma unroll
    for (int kk = 0; kk < 64; kk += 32) {
      const int gq = (kk >> 3) + (lane >> 4);
      short8 af[4], bfr[4];
#pragma unroll
      for (int mt = 0; mt < 4; ++mt) {
        const int row = wm + mt * 16 + l15;
        af[mt] = *(const short8*)&As[row * 64 + ((gq ^ (row & 7)) << 3)];
      }
#pragma unroll
      for (int nt = 0; nt < 4; ++nt) {
        const int row = wn + nt * 16 + l15;
        bfr[nt] = *(const short8*)&Bs[row * 64 + ((gq ^ (row & 7)) << 3)];
      }
#pragma unroll
      for (int mt = 0; mt < 4; ++mt)
#pragma unroll
        for (int nt = 0; nt < 4; ++nt)
          acc[mt][nt] = __builtin_amdgcn_mfma_f32_16x16x32_bf16(
              af[mt], bfr[nt], acc[mt][nt], 0, 0, 0);
    }
    __syncthreads();
  }

  const int r0 = (lane >> 4) * 4;
  float* o = out + (long long)bz * sC;
  const float* lrow = lsum + (long long)bz * sL;
#pragma unroll
  for (int mt = 0; mt < 4; ++mt) {
#pragma unroll
    for (int nt = 0; nt < 4; ++nt) {
      const int n = n0 + wn + nt * 16 + l15;
      const float inv = 1.f / lrow[n];
#pragma unroll
      for (int r = 0; r < 4; ++r) {
        const int m = m0 + wm + mt * 16 + r0 + r;
        atomicAdd(&o[(long long)m * 4096 + n], acc[mt][nt][r] * inv);
      }
    }
  }
}

extern "C" void kernel_launch(void* const* d_in, const int* in_sizes, int n_in,
                              void* d_out, int out_size, void* d_ws, size_t ws_size,
                              hipStream_t stream) {
  const float* x     = (const float*)d_in[0];
  const float* gamma = (const float*)d_in[1];
  const float* beta  = (const float*)d_in[2];
  const float* wq    = (const float*)d_in[3];
  const float* bq    = (const float*)d_in[4];
  const float* wk    = (const float*)d_in[5];
  const float* bk    = (const float*)d_in[6];
  const float* wv    = (const float*)d_in[7];
  const float* bv    = (const float*)d_in[8];
  float* out = (float*)d_out;

  const long long sTok = 4096LL * 512;     // per-batch token-major elems
  const long long sQK8 = 4096LL * 1024;    // per-batch qk8 bytes
  const long long sS   = 4096LL * 4096;

  char* ws = (char*)d_ws;
  float* scale = (float*)ws;                                // 8 KB
  float* shift = (float*)(ws + 8192);                       // 8 KB
  unsigned short* w16 = (unsigned short*)(ws + 16384);      // [wq;wk;wv] bf16
  unsigned short* xnt = (unsigned short*)(ws + 1589248);    // (B,N,C) bf16
  unsigned char*  qk8 = (unsigned char*)(ws + 18366464);    // (B,N,1024) fp8
  unsigned short* vv  = (unsigned short*)(ws + 51920896);   // (B,C,N) bf16

  const bool full = ws_size >= 202982400ULL;

  float* lsum;
  int nzero;
  if (full) {
    lsum = (float*)(ws + 202915840);   // 4*4096 floats, then 256 gsums floats
    nzero = 16384 + 256;
  } else {
    lsum = (float*)(ws + 102252544);   // 4096 floats, then 256 gsums floats
    nzero = 4096 + 256;
  }
  float* gsums = lsum + nzero - 256;

  // wcvt (768 blocks) + zero lsum/gsums (tail blocks), one launch
  wcvt_zero_kernel<<<768 + (nzero + 255) / 256, 256, 0, stream>>>(
      wq, wk, wv, w16, lsum, nzero);
  gn_partial_kernel<<<1024, 256, 0, stream>>>(x, gsums, out);  // + out := x
  gn_finalize_kernel<<<8, 256, 0, stream>>>(gsums, gamma, beta, scale, shift);
  norm_transpose_kernel<<<dim3(64, 8, 4), 256, 0, stream>>>(x, scale, shift, xnt);

  // QK-proj -> fp8: qk8[token][o], o in [0,1024) = [q ; k]
  gemm_tn_kernel<6><<<dim3(8, 32, 4), 256, 0, stream>>>(
      w16, xnt, qk8, bq, bk, 512, 512, 1024, 512, 0, sTok, sQK8);
  // V: (B,C,N) = Wv * Xn  (bf16)
  gemm_tn_kernel<2><<<dim3(4, 32, 4), 256, 0, stream>>>(
      w16 + 524288, xnt, vv, bv, nullptr, 512, 512, 4096, 512, 0, sTok, sTok);

  if (full) {
    unsigned short* S = (unsigned short*)(ws + 68698112);  // (B,N,N) bf16
    sgemm_fp8_kernel<<<dim3(32, 32, 4), 256, 0, stream>>>(
        qk8 + 512, qk8, S, lsum, sQK8, sQK8, sS, 4096);
    // out += V * P^T / lsum   (split-K x2, XCD-grouped, atomic)
    pv_kernel<<<1024, 256, 0, stream>>>(
        vv, S, out, lsum, sTok, sS, sTok, 4096);
  } else {
    unsigned short* S = (unsigned short*)(ws + 68698112);  // (N,N) bf16
    for (int b = 0; b < 4; ++b) {
      if (b) zero_kernel<<<16, 256, 0, stream>>>(lsum, 4096);
      sgemm_fp8_kernel<<<dim3(32, 32, 1), 256, 0, stream>>>(
          qk8 + (long long)b * sQK8 + 512, qk8 + (long long)b * sQK8, S, lsum,
          0, 0, 0, 0);
      pv_kernel<<<256, 256, 0, stream>>>(
          vv + (long long)b * sTok, S, out + (long long)b * sTok, lsum,
          0, 0, 0, 0);
    }
  }
}

// Round 8
// 281.773 us; speedup vs baseline: 1.1364x; 1.1364x over previous
//
#include <hip/hip_runtime.h>
#include <cstdint>

typedef __attribute__((ext_vector_type(8))) short short8;
typedef __attribute__((ext_vector_type(4))) float floatx4;
typedef __attribute__((ext_vector_type(8))) int intx8;

__device__ __forceinline__ unsigned short f2bf(float f) {
  unsigned int u = __float_as_uint(f);
  u += 0x7fffu + ((u >> 16) & 1u);   // RNE, finite inputs
  return (unsigned short)(u >> 16);
}

// ---------------- GroupNorm partial sums: 1024 blocks ----------------------
__global__ __launch_bounds__(256) void gn_partial_kernel(
    const float* __restrict__ x, float* __restrict__ gsums) {
  const int b = blockIdx.x >> 8;
  const int g = (blockIdx.x >> 3) & 31;
  const int e = blockIdx.x & 7;
  const long long off = ((long long)(b * 512 + g * 16)) * 4096;
  const float4* xp = (const float4*)(x + off) + e * 2048;
  float s = 0.f, ss = 0.f;
  for (int i = threadIdx.x; i < 2048; i += 256) {
    float4 v = xp[i];
    s  += v.x + v.y + v.z + v.w;
    ss += v.x * v.x + v.y * v.y + v.z * v.z + v.w * v.w;
  }
  for (int off2 = 32; off2; off2 >>= 1) { s += __shfl_down(s, off2); ss += __shfl_down(ss, off2); }
  __shared__ float sb[8];
  const int lane = threadIdx.x & 63, wave = threadIdx.x >> 6;
  if (lane == 0) { sb[wave] = s; sb[4 + wave] = ss; }
  __syncthreads();
  if (threadIdx.x == 0) {
    atomicAdd(gsums + (b * 32 + g) * 2,     sb[0] + sb[1] + sb[2] + sb[3]);
    atomicAdd(gsums + (b * 32 + g) * 2 + 1, sb[4] + sb[5] + sb[6] + sb[7]);
  }
}

// ---------------- GroupNorm finalize: scale/shift per (b,c) ----------------
__global__ __launch_bounds__(256) void gn_finalize_kernel(
    const float* __restrict__ gsums, const float* __restrict__ gamma,
    const float* __restrict__ beta, float* __restrict__ scale,
    float* __restrict__ shift) {
  const int i = blockIdx.x * 256 + threadIdx.x;  // 0..2047
  const int b = i >> 9;
  const int c = i & 511;
  const int g = c >> 4;
  const float S  = gsums[(b * 32 + g) * 2];
  const float SS = gsums[(b * 32 + g) * 2 + 1];
  const float mean = S * (1.f / 65536.f);
  const float var  = SS * (1.f / 65536.f) - mean * mean;
  const float inv  = rsqrtf(var + 1e-5f);
  const float sc = gamma[c] * inv;
  scale[i] = sc;
  shift[i] = beta[c] - mean * sc;
}

// -------- weights fp32 -> bf16, fused with scratch zeroing -----------------
__global__ __launch_bounds__(256) void wcvt_zero_kernel(
    const float* __restrict__ wq, const float* __restrict__ wk,
    const float* __restrict__ wv, unsigned short* __restrict__ w16,
    float* __restrict__ zp, int nzero) {
  const int gi = blockIdx.x * 256 + threadIdx.x;
  if (gi < 196608) {
    const int m = gi >> 16;            // 0..2
    const int i = gi & 65535;          // *4 elems
    const float* src = (m == 0) ? wq : (m == 1) ? wk : wv;
    float4 v = *((const float4*)src + i);
    ushort4 o;
    o.x = f2bf(v.x); o.y = f2bf(v.y); o.z = f2bf(v.z); o.w = f2bf(v.w);
    *((ushort4*)(w16 + (long long)m * 262144) + i) = o;
  } else {
    const int zi = gi - 196608;
    if (zi < nzero) zp[zi] = 0.f;
  }
}

// -------- normalize + transpose: x (B,C,N) fp32 -> xnt (B,N,C) bf16 --------
__global__ __launch_bounds__(256) void norm_transpose_kernel(
    const float* __restrict__ x, const float* __restrict__ scale,
    const float* __restrict__ shift, unsigned short* __restrict__ xnt) {
  const int b = blockIdx.z;
  const int n0 = blockIdx.x * 64;
  const int c0 = blockIdx.y * 64;
  const int t = threadIdx.x;
  __shared__ unsigned short tile[64][65];
  {
    const int cl = t >> 2;
    const int nc = (t & 3) * 16;
    const int c = c0 + cl;
    const float* xp = x + ((long long)b * 512 + c) * 4096 + n0 + nc;
    const float sc = scale[b * 512 + c];
    const float sh = shift[b * 512 + c];
#pragma unroll
    for (int j = 0; j < 16; j += 4) {
      float4 v = *(const float4*)(xp + j);
      tile[cl][nc + j + 0] = f2bf(v.x * sc + sh);
      tile[cl][nc + j + 1] = f2bf(v.y * sc + sh);
      tile[cl][nc + j + 2] = f2bf(v.z * sc + sh);
      tile[cl][nc + j + 3] = f2bf(v.w * sc + sh);
    }
  }
  __syncthreads();
  {
    const int nl = t >> 2;
    const int cc = (t & 3) * 16;
    union { unsigned short u[16]; uint4 q[2]; } o;
#pragma unroll
    for (int j = 0; j < 16; ++j) o.u[j] = tile[cc + j][nl];
    unsigned short* op = xnt + ((long long)b * 4096 + n0 + nl) * 512 + c0 + cc;
    *((uint4*)op) = o.q[0];
    *((uint4*)op + 1) = o.q[1];
  }
}

// ---------------- zero scratch (per-batch path re-zero) --------------------
__global__ __launch_bounds__(256) void zero_kernel(float* __restrict__ p, int n) {
  const int i = blockIdx.x * 256 + threadIdx.x;
  if (i < n) p[i] = 0.f;
}

// ---------------- TN GEMM (bf16), m97 structure + LDS xor-swizzle ----------
// C[m,n] = sum_k A[m*lda+k] * B[n*ldb+k]
// EPI: 2 = bf16 out + bias[m] (LDS-bounce coalesced store)
//      6 = QK-proj: fp8 e4m3 out TRANSPOSED (rows=col-dim tokens), bias[m]
//          split bias/bias2 at m=512; C treated as u8, ldc/sC in bytes.
template <int EPI>
__global__ __launch_bounds__(256) void gemm_tn_kernel(
    const unsigned short* __restrict__ A, const unsigned short* __restrict__ B,
    void* __restrict__ C, const float* __restrict__ bias,
    const float* __restrict__ bias2,
    int lda, int ldb, int ldc, int K,
    long long sA, long long sB, long long sC) {
  const int tid = threadIdx.x;
  const int lane = tid & 63;
  const int wave = tid >> 6;
  const int m0 = blockIdx.x * 128;
  const int n0 = blockIdx.y * 128;
  const int bz = blockIdx.z;
  A += (long long)bz * sA;
  B += (long long)bz * sB;

  __shared__ unsigned short smem[17408];  // 34816 B
  unsigned short* As = smem;
  unsigned short* Bs = smem + 8192;

  floatx4 acc[4][4];
#pragma unroll
  for (int i = 0; i < 4; ++i)
#pragma unroll
    for (int j = 0; j < 4; ++j) acc[i][j] = (floatx4){0.f, 0.f, 0.f, 0.f};

  const unsigned short* ag[4];
  const unsigned short* bg[4];
  unsigned ldsoff[4];
#pragma unroll
  for (int i = 0; i < 4; ++i) {
    const int idx = i * 256 + tid;   // 16B granule within 128x64 tile
    const int r = idx >> 3;
    const int g = idx & 7;
    const int gs = g ^ (r & 7);      // xor-swizzled global granule
    ag[i] = A + (long long)(m0 + r) * lda + gs * 8;
    bg[i] = B + (long long)(n0 + r) * ldb + gs * 8;
    ldsoff[i] = (unsigned)(i * 256 + wave * 64) * 8;
  }

  const int l15 = lane & 15;
  const int wm = (wave >> 1) * 64;
  const int wn = (wave & 1) * 64;

  for (int k0 = 0; k0 < K; k0 += 64) {
#pragma unroll
    for (int i = 0; i < 4; ++i) {
      __builtin_amdgcn_global_load_lds(
          (const __attribute__((address_space(1))) void*)(ag[i] + k0),
          (__attribute__((address_space(3))) void*)(As + ldsoff[i]), 16, 0, 0);
      __builtin_amdgcn_global_load_lds(
          (const __attribute__((address_space(1))) void*)(bg[i] + k0),
          (__attribute__((address_space(3))) void*)(Bs + ldsoff[i]), 16, 0, 0);
    }
    __syncthreads();
#pragma unroll
    for (int kk = 0; kk < 64; kk += 32) {
      const int gq = (kk >> 3) + (lane >> 4);
      short8 af[4], bfr[4];
#pragma unroll
      for (int mt = 0; mt < 4; ++mt) {
        const int row = wm + mt * 16 + l15;
        af[mt] = *(const short8*)&As[row * 64 + ((gq ^ (row & 7)) << 3)];
      }
#pragma unroll
      for (int nt = 0; nt < 4; ++nt) {
        const int row = wn + nt * 16 + l15;
        bfr[nt] = *(const short8*)&Bs[row * 64 + ((gq ^ (row & 7)) << 3)];
      }
#pragma unroll
      for (int mt = 0; mt < 4; ++mt)
#pragma unroll
        for (int nt = 0; nt < 4; ++nt)
          acc[mt][nt] = __builtin_amdgcn_mfma_f32_16x16x32_bf16(
              af[mt], bfr[nt], acc[mt][nt], 0, 0, 0);
    }
    __syncthreads();
  }
  // After final barrier, smem is reusable.

  const int r0 = (lane >> 4) * 4;

  if (EPI == 6) {
    // D row (r-quad) = output channel o (A=weights), col (l15) = token.
    unsigned char* t8 = (unsigned char*)smem;
    const float* bp = (m0 >= 512) ? bias2 : bias;
    const int mb = m0 & 511;
#pragma unroll
    for (int mt = 0; mt < 4; ++mt) {
      const int ml = wm + mt * 16 + r0;   // o-local, multiple of 4
      const float b0 = bp[mb + ml], b1 = bp[mb + ml + 1];
      const float b2 = bp[mb + ml + 2], b3 = bp[mb + ml + 3];
      const int gw = ml >> 4;
      const int mby = ml & 15;
#pragma unroll
      for (int nt = 0; nt < 4; ++nt) {
        const int nl = wn + nt * 16 + l15;  // token-local
        int p = __builtin_amdgcn_cvt_pk_fp8_f32(acc[mt][nt][0] + b0,
                                                acc[mt][nt][1] + b1, 0, false);
        p = __builtin_amdgcn_cvt_pk_fp8_f32(acc[mt][nt][2] + b2,
                                            acc[mt][nt][3] + b3, p, true);
        *(int*)&t8[nl * 128 + ((gw ^ (nl & 7)) << 4) + mby] = p;
      }
    }
    __syncthreads();
    unsigned char* o8 = (unsigned char*)C + (long long)bz * sC;
#pragma unroll
    for (int t = 0; t < 4; ++t) {
      const int gid = t * 256 + tid;
      const int row = gid >> 3;    // token 0..127
      const int gc = gid & 7;
      uint4 v = *(const uint4*)&t8[row * 128 + ((gc ^ (row & 7)) << 4)];
      *(uint4*)&o8[(long long)(n0 + row) * ldc + m0 + gc * 16] = v;
    }
    return;
  }

  // EPI 2: bf16 out + bias[m], LDS bounce
#pragma unroll
  for (int mt = 0; mt < 4; ++mt) {
#pragma unroll
    for (int nt = 0; nt < 4; ++nt) {
      const int nl = wn + nt * 16 + l15;
#pragma unroll
      for (int r = 0; r < 4; ++r) {
        const int ml = wm + mt * 16 + r0 + r;
        smem[ml * 136 + nl] = f2bf(acc[mt][nt][r] + bias[m0 + ml]);
      }
    }
  }
  __syncthreads();
  {
    unsigned short* o = (unsigned short*)C + (long long)bz * sC;
#pragma unroll
    for (int j = 0; j < 8; ++j) {
      const int gid = j * 256 + tid;
      const int m = gid >> 4;
      const int gc = gid & 15;
      short8 v = *(const short8*)&smem[m * 136 + gc * 8];
      *(short8*)&o[(long long)(m0 + m) * ldc + n0 + gc * 8] = v;
    }
  }
}

// -------- S = exp(QK^T * scl) via MX-fp8 MFMA (unit scales) ----------------
__global__ __launch_bounds__(256) void sgemm_fp8_kernel(
    const unsigned char* __restrict__ A, const unsigned char* __restrict__ B,
    unsigned short* __restrict__ S, float* __restrict__ lsum,
    long long sA, long long sB, long long sC, long long sL) {
  const int tid = threadIdx.x;
  const int lane = tid & 63;
  const int wave = tid >> 6;
  const int quad = lane >> 4;
  const int l15 = lane & 15;
  const int j0 = blockIdx.x * 128;
  const int i0 = blockIdx.y * 128;
  const int bz = blockIdx.z;
  A += (long long)bz * sA;
  B += (long long)bz * sB;

  __shared__ unsigned short smem[17408];        // 34816 B
  unsigned char* As = (unsigned char*)smem;     // 128 x 128 B
  unsigned char* Bs = (unsigned char*)smem + 16384;

  floatx4 acc[4][4];
#pragma unroll
  for (int i = 0; i < 4; ++i)
#pragma unroll
    for (int j = 0; j < 4; ++j) acc[i][j] = (floatx4){0.f, 0.f, 0.f, 0.f};

  const unsigned char* ag[4];
  const unsigned char* bg[4];
  unsigned ldsoff[4];
#pragma unroll
  for (int i = 0; i < 4; ++i) {
    const int idx = i * 256 + tid;   // 16B granule within 128x128B tile
    const int r = idx >> 3;
    const int g = idx & 7;
    const int gs = g ^ (r & 7);
    ag[i] = A + (long long)(j0 + r) * 1024 + gs * 16;
    bg[i] = B + (long long)(i0 + r) * 1024 + gs * 16;
    ldsoff[i] = (unsigned)(i * 256 + wave * 64) * 16;
  }

  const int wj = (wave >> 1) * 64;
  const int wi = (wave & 1) * 64;

  for (int k0 = 0; k0 < 512; k0 += 128) {
#pragma unroll
    for (int i = 0; i < 4; ++i) {
      __builtin_amdgcn_global_load_lds(
          (const __attribute__((address_space(1))) void*)(ag[i] + k0),
          (__attribute__((address_space(3))) void*)(As + ldsoff[i]), 16, 0, 0);
      __builtin_amdgcn_global_load_lds(
          (const __attribute__((address_space(1))) void*)(bg[i] + k0),
          (__attribute__((address_space(3))) void*)(Bs + ldsoff[i]), 16, 0, 0);
    }
    __syncthreads();
    intx8 af[4], bq[4];
#pragma unroll
    for (int t = 0; t < 4; ++t) {
      {
        const int row = wj + t * 16 + l15;
        const int r7 = row & 7;
        const uint4 x0 = *(const uint4*)(As + row * 128 + (((2 * quad) ^ r7) << 4));
        const uint4 x1 = *(const uint4*)(As + row * 128 + (((2 * quad + 1) ^ r7) << 4));
        af[t] = (intx8){(int)x0.x, (int)x0.y, (int)x0.z, (int)x0.w,
                        (int)x1.x, (int)x1.y, (int)x1.z, (int)x1.w};
      }
      {
        const int row = wi + t * 16 + l15;
        const int r7 = row & 7;
        const uint4 x0 = *(const uint4*)(Bs + row * 128 + (((2 * quad) ^ r7) << 4));
        const uint4 x1 = *(const uint4*)(Bs + row * 128 + (((2 * quad + 1) ^ r7) << 4));
        bq[t] = (intx8){(int)x0.x, (int)x0.y, (int)x0.z, (int)x0.w,
                        (int)x1.x, (int)x1.y, (int)x1.z, (int)x1.w};
      }
    }
#pragma unroll
    for (int jt = 0; jt < 4; ++jt)
#pragma unroll
      for (int it = 0; it < 4; ++it)
        acc[jt][it] = __builtin_amdgcn_mfma_scale_f32_16x16x128_f8f6f4(
            af[jt], bq[it], acc[jt][it], 0, 0, 0, 127, 0, 127);
    __syncthreads();
  }

  // Epilogue: e = exp(score*SCL); tile [i][j] bf16 (pad 136); b64 writes.
  const float SCL = 0.044194173824159216f;  // 1/sqrt(512)
  const int jr = quad * 4;
  float rs_it[4] = {0.f, 0.f, 0.f, 0.f};
#pragma unroll
  for (int jt = 0; jt < 4; ++jt) {
#pragma unroll
    for (int it = 0; it < 4; ++it) {
      const int il = wi + it * 16 + l15;
      const int jl = wj + jt * 16 + jr;
      unsigned long long pk = 0;
#pragma unroll
      for (int r = 0; r < 4; ++r) {
        const float e = __expf(acc[jt][it][r] * SCL);
        rs_it[it] += e;
        pk |= (unsigned long long)(__float_as_uint(e) >> 16) << (16 * r);
      }
      *(unsigned long long*)&smem[il * 136 + jl] = pk;
    }
  }
  float* lrow = lsum + (long long)bz * sL;
#pragma unroll
  for (int it = 0; it < 4; ++it) {
    float rs = rs_it[it];
    rs += __shfl_xor(rs, 16);
    rs += __shfl_xor(rs, 32);
    if (quad == 0) atomicAdd(lrow + i0 + wi + it * 16 + l15, rs);
  }
  __syncthreads();
  unsigned short* o = S + (long long)bz * sC;
#pragma unroll
  for (int t = 0; t < 8; ++t) {
    const int gid = t * 256 + tid;
    const int row = gid >> 4;
    const int gc = gid & 15;
    short8 v = *(const short8*)&smem[row * 136 + gc * 8];
    *(short8*)&o[(long long)(i0 + row) * 4096 + j0 + gc * 8] = v;
  }
}

// -------- PV: out[c,n] = sum_j V[c,j] P[n,j] / lsum[n] + x[c,n] ------------
// 1D grid, XCD-grouped decode: the 4 m-tiles of one (n-strip,batch) land on
// the SAME XCD (id%8) in consecutive slots -> shared S-strip stays in L2.
__global__ __launch_bounds__(256) void pv_kernel(
    const unsigned short* __restrict__ A,   // V rows (c), stride 4096
    const unsigned short* __restrict__ B,   // S rows (n), stride 4096
    float* __restrict__ out, const float* __restrict__ res,
    const float* __restrict__ lsum,
    long long sA, long long sB, long long sC, long long sL) {
  const int id = blockIdx.x;
  const int xcd = id & 7;
  const int slot = id >> 3;
  const int m0 = (slot & 3) * 128;
  const int grp = xcd + 8 * (slot >> 2);   // (n-strip, batch) group
  const int n0 = (grp & 31) * 128;
  const int bz = grp >> 5;
  A += (long long)bz * sA;
  B += (long long)bz * sB;

  const int tid = threadIdx.x;
  const int lane = tid & 63;
  const int wave = tid >> 6;

  __shared__ unsigned short As[8192];
  __shared__ unsigned short Bs[8192];

  floatx4 acc[4][4];
#pragma unroll
  for (int i = 0; i < 4; ++i)
#pragma unroll
    for (int j = 0; j < 4; ++j) acc[i][j] = (floatx4){0.f, 0.f, 0.f, 0.f};

  const unsigned short* ag[4];
  const unsigned short* bg[4];
  unsigned ldsoff[4];
#pragma unroll
  for (int i = 0; i < 4; ++i) {
    const int idx = i * 256 + tid;
    const int r = idx >> 3;
    const int g = idx & 7;
    const int gs = g ^ (r & 7);
    ag[i] = A + (long long)(m0 + r) * 4096 + gs * 8;
    bg[i] = B + (long long)(n0 + r) * 4096 + gs * 8;
    ldsoff[i] = (unsigned)(i * 256 + wave * 64) * 8;
  }

  const int l15 = lane & 15;
  const int wm = (wave >> 1) * 64;
  const int wn = (wave & 1) * 64;

  for (int k0 = 0; k0 < 4096; k0 += 64) {
#pragma unroll
    for (int i = 0; i < 4; ++i) {
      __builtin_amdgcn_global_load_lds(
          (const __attribute__((address_space(1))) void*)(ag[i] + k0),
          (__attribute__((address_space(3))) void*)(As + ldsoff[i]), 16, 0, 0);
      __builtin_amdgcn_global_load_lds(
          (const __attribute__((address_space(1))) void*)(bg[i] + k0),
          (__attribute__((address_space(3))) void*)(Bs + ldsoff[i]), 16, 0, 0);
    }
    __syncthreads();
#pragma unroll
    for (int kk = 0; kk < 64; kk += 32) {
      const int gq = (kk >> 3) + (lane >> 4);
      short8 af[4], bfr[4];
#pragma unroll
      for (int mt = 0; mt < 4; ++mt) {
        const int row = wm + mt * 16 + l15;
        af[mt] = *(const short8*)&As[row * 64 + ((gq ^ (row & 7)) << 3)];
      }
#pragma unroll
      for (int nt = 0; nt < 4; ++nt) {
        const int row = wn + nt * 16 + l15;
        bfr[nt] = *(const short8*)&Bs[row * 64 + ((gq ^ (row & 7)) << 3)];
      }
#pragma unroll
      for (int mt = 0; mt < 4; ++mt)
#pragma unroll
        for (int nt = 0; nt < 4; ++nt)
          acc[mt][nt] = __builtin_amdgcn_mfma_f32_16x16x32_bf16(
              af[mt], bfr[nt], acc[mt][nt], 0, 0, 0);
    }
    __syncthreads();
  }

  const int r0 = (lane >> 4) * 4;
  float* o = out + (long long)bz * sC;
  const float* rr = res + (long long)bz * sC;
  const float* lrow = lsum + (long long)bz * sL;
#pragma unroll
  for (int mt = 0; mt < 4; ++mt) {
#pragma unroll
    for (int nt = 0; nt < 4; ++nt) {
      const int n = n0 + wn + nt * 16 + l15;
      const float inv = 1.f / lrow[n];
#pragma unroll
      for (int r = 0; r < 4; ++r) {
        const int m = m0 + wm + mt * 16 + r0 + r;
        const long long off = (long long)m * 4096 + n;
        o[off] = acc[mt][nt][r] * inv + rr[off];
      }
    }
  }
}

extern "C" void kernel_launch(void* const* d_in, const int* in_sizes, int n_in,
                              void* d_out, int out_size, void* d_ws, size_t ws_size,
                              hipStream_t stream) {
  const float* x     = (const float*)d_in[0];
  const float* gamma = (const float*)d_in[1];
  const float* beta  = (const float*)d_in[2];
  const float* wq    = (const float*)d_in[3];
  const float* bq    = (const float*)d_in[4];
  const float* wk    = (const float*)d_in[5];
  const float* bk    = (const float*)d_in[6];
  const float* wv    = (const float*)d_in[7];
  const float* bv    = (const float*)d_in[8];
  float* out = (float*)d_out;

  const long long sTok = 4096LL * 512;     // per-batch token-major elems
  const long long sQK8 = 4096LL * 1024;    // per-batch qk8 bytes
  const long long sS   = 4096LL * 4096;

  char* ws = (char*)d_ws;
  float* scale = (float*)ws;                                // 8 KB
  float* shift = (float*)(ws + 8192);                       // 8 KB
  unsigned short* w16 = (unsigned short*)(ws + 16384);      // [wq;wk;wv] bf16
  unsigned short* xnt = (unsigned short*)(ws + 1589248);    // (B,N,C) bf16
  unsigned char*  qk8 = (unsigned char*)(ws + 18366464);    // (B,N,1024) fp8
  unsigned short* vv  = (unsigned short*)(ws + 51920896);   // (B,C,N) bf16

  const bool full = ws_size >= 202982400ULL;

  float* lsum;
  int nzero;
  if (full) {
    lsum = (float*)(ws + 202915840);   // 4*4096 floats, then 256 gsums floats
    nzero = 16384 + 256;
  } else {
    lsum = (float*)(ws + 102252544);   // 4096 floats, then 256 gsums floats
    nzero = 4096 + 256;
  }
  float* gsums = lsum + nzero - 256;

  // wcvt (768 blocks) + zero lsum/gsums (tail blocks), one launch
  wcvt_zero_kernel<<<768 + (nzero + 255) / 256, 256, 0, stream>>>(
      wq, wk, wv, w16, lsum, nzero);
  gn_partial_kernel<<<1024, 256, 0, stream>>>(x, gsums);
  gn_finalize_kernel<<<8, 256, 0, stream>>>(gsums, gamma, beta, scale, shift);
  norm_transpose_kernel<<<dim3(64, 8, 4), 256, 0, stream>>>(x, scale, shift, xnt);

  // QK-proj -> fp8: qk8[token][o], o in [0,1024) = [q ; k]
  gemm_tn_kernel<6><<<dim3(8, 32, 4), 256, 0, stream>>>(
      w16, xnt, qk8, bq, bk, 512, 512, 1024, 512, 0, sTok, sQK8);
  // V: (B,C,N) = Wv * Xn  (bf16)
  gemm_tn_kernel<2><<<dim3(4, 32, 4), 256, 0, stream>>>(
      w16 + 524288, xnt, vv, bv, nullptr, 512, 512, 4096, 512, 0, sTok, sTok);

  if (full) {
    unsigned short* S = (unsigned short*)(ws + 68698112);  // (B,N,N) bf16
    sgemm_fp8_kernel<<<dim3(32, 32, 4), 256, 0, stream>>>(
        qk8 + 512, qk8, S, lsum, sQK8, sQK8, sS, 4096);
    // out = V * P^T / lsum + x   (XCD-grouped, direct store)
    pv_kernel<<<512, 256, 0, stream>>>(
        vv, S, out, x, lsum, sTok, sS, sTok, 4096);
  } else {
    unsigned short* S = (unsigned short*)(ws + 68698112);  // (N,N) bf16
    for (int b = 0; b < 4; ++b) {
      if (b) zero_kernel<<<16, 256, 0, stream>>>(lsum, 4096);
      sgemm_fp8_kernel<<<dim3(32, 32, 1), 256, 0, stream>>>(
          qk8 + (long long)b * sQK8 + 512, qk8 + (long long)b * sQK8, S, lsum,
          0, 0, 0, 0);
      pv_kernel<<<128, 256, 0, stream>>>(
          vv + (long long)b * sTok, S, out + (long long)b * sTok,
          x + (long long)b * sTok, lsum, 0, 0, 0, 0);
    }
  }
}